// Round 6
// baseline (148.222 us; speedup 1.0000x reference)
//
#include <hip/hip_runtime.h>

// Firefly optimizer, round 6: 4 dispatches (3 scans + fused scan+final).
// Overhead model from R3/R4/R5: ~59us fixed graph overhead + ~12us/dispatch
// + exec. R6 cuts: (a) cost (cospif x 9.4M) removed from phase A -- the MFMA
// gate never uses cost; slow path computes cost16() on demand and rejects
// i==j by integer compare; (b) the last scan uses an i-tile x ALL-j
// decomposition (128 blocks, j streamed in 4 LDS chunks) so each block owns
// the complete attraction for its 128 i-rows and applies update 3 -> d_out
// in the same dispatch (no 5th kernel).
// Gate math unchanged (R3..R5, passed): D = g_bf16 + (T-sqi)/2, hot <=>
// D > sqj/2; exact-fp32 slow path; hot pairs carried as compact lists.

#define SPECIES 4
#define POP     4096
#define DIM     16
#define NSI     (SPECIES * POP)
#define T_CUT   10.0f
#define NBLK    512        // scan grid: 4 species x 32 itiles x 4 jchunks
#define CAP_B   64         // hot-list entries per block
#define LCAP    128        // compacted list cap (expected ~6)
#define ITR     128        // i-rows per block
#define JSPAN   1024       // j-rows per LDS tile

typedef __attribute__((ext_vector_type(8)))  short short8;    // 8 bf16
typedef __attribute__((ext_vector_type(16))) float floatx16;  // MFMA C/D

__device__ __forceinline__ unsigned short f2bf(float f) {
    unsigned u = __float_as_uint(f);
    u += 0x7FFFu + ((u >> 16) & 1u);
    return (unsigned short)(u >> 16);
}

// Exact fp32 updated position of `row` at this step (post-mix indexing).
__device__ __forceinline__ void compute_x16(
        const float* __restrict__ xprev, const float* __restrict__ nz,
        float alpha, int mix, int upd, int row,
        const int* __restrict__ lrow, const float* __restrict__ lvec, int nl,
        float v[16]) {
    int src = row;
    if (upd && mix) {
        int i = row & (POP - 1);
        if (i >= POP / 2)
            src = ((((row >> 12) + SPECIES - 1) & (SPECIES - 1)) << 12) | i;
    }
    const float* xp = xprev + (size_t)src * DIM;
    if (!upd) {
        #pragma unroll
        for (int d = 0; d < 16; ++d) v[d] = xp[d];
        return;
    }
    const float* np = nz + (size_t)src * DIM;
    float add[16];
    #pragma unroll
    for (int d = 0; d < 16; ++d) add[d] = 0.0f;
    for (int e = 0; e < nl; ++e) {        // nl ~ 6
        if (lrow[e] == src) {
            #pragma unroll
            for (int d = 0; d < 16; ++d) add[d] += lvec[e * 16 + d];
        }
    }
    #pragma unroll
    for (int d = 0; d < 16; ++d) {
        float xn = (xp[d] + add[d]) + alpha * (np[d] - 0.5f) * 8.0f;
        v[d] = fminf(fmaxf(xn, -4.0f), 4.0f);
    }
}

__device__ __forceinline__ float cost16(const float v[16]) {
    float sqv = 0.0f, cv = 0.0f;
    #pragma unroll
    for (int d = 0; d < 16; ++d) {
        sqv = fmaf(v[d], v[d], sqv);
        cv += cospif(2.0f * v[d]);
    }
    return 10.0f * DIM + sqv - 10.0f * cv;
}

// ---- scan: build x_s tile in LDS, MFMA gate, export hot list ---------------
__global__ __launch_bounds__(256) void scan_kernel(
        const float* __restrict__ xprev, const float* __restrict__ nz,
        float alpha, int mix, int upd,
        float* __restrict__ xcur,                       // materialize x_s
        const int* __restrict__ cin, const int* __restrict__ rin,
        const float* __restrict__ vin, int have_in,
        int* __restrict__ cout, int* __restrict__ rout,
        float* __restrict__ vout) {
    __shared__ unsigned short xb_i[ITR * DIM];          //  4 KB
    __shared__ unsigned short xb_j[JSPAN * DIM];        // 32 KB
    __shared__ float sq_i[ITR];                         // 0.5 KB
    __shared__ float sq_j[JSPAN];                       //  4 KB
    __shared__ int   lrow[LCAP];                        // 0.5 KB
    __shared__ float lvec[LCAP * 16];                   //  8 KB
    __shared__ int   nl_s, cnt_s;

    const int tid = threadIdx.x;
    const int b   = blockIdx.x;
    const int jc  = b & 3;
    const int it  = (b >> 2) & 31;
    const int sp  = b >> 7;
    const int sb  = sp * POP;
    const int i0  = it * ITR;
    const int j0  = jc * JSPAN;

    if (tid == 0) { nl_s = 0; cnt_s = 0; }
    __syncthreads();

    if (have_in) {
        for (int t = tid; t < NBLK; t += 256) {
            int c = cin[t];
            if (c > 0) {
                c = min(c, CAP_B);
                int base = atomicAdd(&nl_s, c);
                for (int e = 0; e < c; ++e) {
                    int slot = base + e;
                    if (slot < LCAP) {
                        lrow[slot] = rin[t * CAP_B + e];
                        for (int d = 0; d < 16; ++d)
                            lvec[slot * 16 + d] = vin[(t * CAP_B + e) * 16 + d];
                    }
                }
            }
        }
    }
    __syncthreads();
    const int nl = min(nl_s, LCAP);

    // phase A: build rows (no cost!)
    for (int r = tid; r < ITR + JSPAN; r += 256) {
        int row = (r < ITR) ? (sb + i0 + r) : (sb + j0 + (r - ITR));
        float v[16];
        compute_x16(xprev, nz, alpha, mix, upd, row, lrow, lvec, nl, v);
        float sqv = 0.0f;
        #pragma unroll
        for (int d = 0; d < 16; ++d) sqv = fmaf(v[d], v[d], sqv);
        if (r < ITR) {
            #pragma unroll
            for (int d = 0; d < 16; ++d) xb_i[r * 16 + d] = f2bf(v[d]);
            sq_i[r] = sqv;
            if (upd && jc == 0) {
                float* xo = xcur + (size_t)row * DIM;
                #pragma unroll
                for (int d = 0; d < 16; ++d) xo[d] = v[d];
            }
        } else {
            int jj = r - ITR;
            #pragma unroll
            for (int d = 0; d < 16; ++d) xb_j[jj * 16 + d] = f2bf(v[d]);
            sq_j[jj] = sqv;
        }
    }
    __syncthreads();

    // phase B: MFMA gate
    const int lane = tid & 63, wave = tid >> 6;
    const int l31 = lane & 31, half = lane >> 5;
    const int iw0 = wave * 32;
    const short8* axi = (const short8*)xb_i;
    const short8* axj = (const short8*)xb_j;
    const short8 afrag = axi[((iw0 + l31) << 1) | half];

    floatx16 c;   // row r -> (r&3) + 8*(r>>2) + 4*half
    {
        const float* sp_ = sq_i + iw0 + 4 * half;
        #pragma unroll
        for (int bq = 0; bq < 4; ++bq)
            #pragma unroll
            for (int t2 = 0; t2 < 4; ++t2)
                c[4 * bq + t2] = 0.5f * (T_CUT - sp_[8 * bq + t2]);
    }

    for (int jt = 0; jt < JSPAN; jt += 32) {
        short8 bfrag = axj[((jt + l31) << 1) | half];
        float  hsqj  = 0.5f * sq_j[jt + l31];
        floatx16 d = __builtin_amdgcn_mfma_f32_32x32x16_bf16(afrag, bfrag, c,
                                                             0, 0, 0);
        float m0 = fmaxf(fmaxf(d[0], d[1]),   fmaxf(d[2], d[3]));
        float m1 = fmaxf(fmaxf(d[4], d[5]),   fmaxf(d[6], d[7]));
        float m2 = fmaxf(fmaxf(d[8], d[9]),   fmaxf(d[10], d[11]));
        float m3 = fmaxf(fmaxf(d[12], d[13]), fmaxf(d[14], d[15]));
        float m  = fmaxf(fmaxf(m0, m1), fmaxf(m2, m3));

        if (__any(m > hsqj)) {
            const int jl = jt + l31;
            #pragma unroll 1
            for (int r = 0; r < 16; ++r) {
                if (d[r] > hsqj) {
                    const int il = iw0 + (r & 3) + 8 * (r >> 2) + 4 * half;
                    const int ig = i0 + il, jg = j0 + jl;
                    if (ig != jg) {                 // diagonal: integer reject
                        float xi[16], xj[16];
                        compute_x16(xprev, nz, alpha, mix, upd,
                                    sb + ig, lrow, lvec, nl, xi);
                        compute_x16(xprev, nz, alpha, mix, upd,
                                    sb + jg, lrow, lvec, nl, xj);
                        float dot = 0.0f;
                        #pragma unroll
                        for (int dd = 0; dd < 16; ++dd)
                            dot = fmaf(xi[dd], xj[dd], dot);
                        float d2 = fmaxf(fmaf(-2.0f, dot,
                                              sq_i[il] + sq_j[jl]), 0.0f);
                        if (d2 < T_CUT && cost16(xi) > cost16(xj)) {
                            float w = 2.0f * expf(-d2);
                            int slot = atomicAdd(&cnt_s, 1);
                            if (slot < CAP_B) {
                                int g = b * CAP_B + slot;
                                rout[g] = sb + ig;
                                #pragma unroll
                                for (int dd = 0; dd < 16; ++dd)
                                    vout[g * 16 + dd] = w * (xj[dd] - xi[dd]);
                            }
                        }
                    }
                }
            }
        }
    }
    __syncthreads();
    if (tid == 0) cout[b] = min(cnt_s, CAP_B);
}

// ---- fused last scan + final update -> d_out -------------------------------
// grid 128 blocks = (species, itile); each block scans ALL j in 4 LDS chunks,
// so it owns the complete attraction for its 128 i-rows.
__global__ __launch_bounds__(256) void final_kernel(
        const float* __restrict__ xprev,
        const float* __restrict__ nzA, float alphaA, int mixA, int updA,
        const float* __restrict__ nzB, float alphaB, int mixB,
        const int* __restrict__ cin, const int* __restrict__ rin,
        const float* __restrict__ vin, int have_in,
        float* __restrict__ out) {
    __shared__ unsigned short xb_i[ITR * DIM];          //  4 KB
    __shared__ unsigned short xb_j[JSPAN * DIM];        // 32 KB
    __shared__ float xi_f[ITR * DIM];                   //  8 KB
    __shared__ float attr_s[ITR * DIM];                 //  8 KB
    __shared__ float sq_i[ITR];
    __shared__ float sq_j[JSPAN];                       //  4 KB
    __shared__ int   lrow[LCAP];
    __shared__ float lvec[LCAP * 16];                   //  8 KB
    __shared__ int   nl_s;

    const int tid = threadIdx.x;
    const int b   = blockIdx.x;        // 0..127
    const int it  = b & 31;
    const int sp  = b >> 5;
    const int sb  = sp * POP;
    const int i0  = it * ITR;

    if (tid == 0) nl_s = 0;
    __syncthreads();
    if (have_in) {
        for (int t = tid; t < NBLK; t += 256) {
            int c = cin[t];
            if (c > 0) {
                c = min(c, CAP_B);
                int base = atomicAdd(&nl_s, c);
                for (int e = 0; e < c; ++e) {
                    int slot = base + e;
                    if (slot < LCAP) {
                        lrow[slot] = rin[t * CAP_B + e];
                        for (int d = 0; d < 16; ++d)
                            lvec[slot * 16 + d] = vin[(t * CAP_B + e) * 16 + d];
                    }
                }
            }
        }
    }
    __syncthreads();
    const int nl = min(nl_s, LCAP);

    // i-rows (keep fp32 copy for the final update) + zero attraction
    for (int r = tid; r < ITR; r += 256) {
        float v[16];
        compute_x16(xprev, nzA, alphaA, mixA, updA, sb + i0 + r,
                    lrow, lvec, nl, v);
        float sqv = 0.0f;
        #pragma unroll
        for (int d = 0; d < 16; ++d) {
            xi_f[r * 16 + d] = v[d];
            xb_i[r * 16 + d] = f2bf(v[d]);
            sqv = fmaf(v[d], v[d], sqv);
        }
        sq_i[r] = sqv;
    }
    for (int t = tid; t < ITR * DIM; t += 256) attr_s[t] = 0.0f;
    __syncthreads();

    const int lane = tid & 63, wave = tid >> 6;
    const int l31 = lane & 31, half = lane >> 5;
    const int iw0 = wave * 32;
    const short8* axi = (const short8*)xb_i;
    const short8* axj = (const short8*)xb_j;
    const short8 afrag = axi[((iw0 + l31) << 1) | half];

    floatx16 c;
    {
        const float* sp_ = sq_i + iw0 + 4 * half;
        #pragma unroll
        for (int bq = 0; bq < 4; ++bq)
            #pragma unroll
            for (int t2 = 0; t2 < 4; ++t2)
                c[4 * bq + t2] = 0.5f * (T_CUT - sp_[8 * bq + t2]);
    }

    for (int chunk = 0; chunk < POP / JSPAN; ++chunk) {
        const int j0 = chunk * JSPAN;
        __syncthreads();                 // previous chunk's MFMA phase done
        for (int r = tid; r < JSPAN; r += 256) {
            float v[16];
            compute_x16(xprev, nzA, alphaA, mixA, updA, sb + j0 + r,
                        lrow, lvec, nl, v);
            float sqv = 0.0f;
            #pragma unroll
            for (int d = 0; d < 16; ++d) {
                xb_j[r * 16 + d] = f2bf(v[d]);
                sqv = fmaf(v[d], v[d], sqv);
            }
            sq_j[r] = sqv;
        }
        __syncthreads();

        for (int jt = 0; jt < JSPAN; jt += 32) {
            short8 bfrag = axj[((jt + l31) << 1) | half];
            float  hsqj  = 0.5f * sq_j[jt + l31];
            floatx16 d = __builtin_amdgcn_mfma_f32_32x32x16_bf16(
                    afrag, bfrag, c, 0, 0, 0);
            float m0 = fmaxf(fmaxf(d[0], d[1]),   fmaxf(d[2], d[3]));
            float m1 = fmaxf(fmaxf(d[4], d[5]),   fmaxf(d[6], d[7]));
            float m2 = fmaxf(fmaxf(d[8], d[9]),   fmaxf(d[10], d[11]));
            float m3 = fmaxf(fmaxf(d[12], d[13]), fmaxf(d[14], d[15]));
            float m  = fmaxf(fmaxf(m0, m1), fmaxf(m2, m3));

            if (__any(m > hsqj)) {
                const int jl = jt + l31;
                #pragma unroll 1
                for (int r = 0; r < 16; ++r) {
                    if (d[r] > hsqj) {
                        const int il = iw0 + (r & 3) + 8 * (r >> 2) + 4 * half;
                        const int ig = i0 + il, jg = j0 + jl;
                        if (ig != jg) {
                            float xi[16], xj[16];
                            #pragma unroll
                            for (int dd = 0; dd < 16; ++dd)
                                xi[dd] = xi_f[il * 16 + dd];
                            compute_x16(xprev, nzA, alphaA, mixA, updA,
                                        sb + jg, lrow, lvec, nl, xj);
                            float dot = 0.0f;
                            #pragma unroll
                            for (int dd = 0; dd < 16; ++dd)
                                dot = fmaf(xi[dd], xj[dd], dot);
                            float d2 = fmaxf(fmaf(-2.0f, dot,
                                    sq_i[il] + sq_j[jl]), 0.0f);
                            if (d2 < T_CUT && cost16(xi) > cost16(xj)) {
                                float w = 2.0f * expf(-d2);
                                #pragma unroll
                                for (int dd = 0; dd < 16; ++dd)
                                    atomicAdd(&attr_s[il * 16 + dd],
                                              w * (xj[dd] - xi[dd]));
                            }
                        }
                    }
                }
            }
        }
    }
    __syncthreads();

    // final update (+ optional mix of THIS update, steps!=4 safety)
    for (int t = tid; t < ITR * DIM; t += 256) {
        int r = t >> 4, d = t & 15;
        int i = i0 + r;
        int grow = sb + i;
        float xn = xi_f[t] + attr_s[t]
                 + alphaB * (nzB[(size_t)grow * DIM + d] - 0.5f) * 8.0f;
        xn = fminf(fmaxf(xn, -4.0f), 4.0f);
        int s_out = (mixB && i >= POP / 2) ? ((sp + 1) & (SPECIES - 1)) : sp;
        out[((size_t)s_out * POP + i) * DIM + d] = xn;
    }
}

extern "C" void kernel_launch(void* const* d_in, const int* in_sizes, int n_in,
                              void* d_out, int out_size, void* d_ws, size_t ws_size,
                              hipStream_t stream) {
    const float* x0    = (const float*)d_in[0];
    const float* noise = (const float*)d_in[1];
    const int steps = in_sizes[1] / in_sizes[0];      // = 4

    float* f     = (float*)d_ws;
    float* xA    = f;                                 // NSI*DIM
    float* xB    = xA + (size_t)NSI * DIM;            // NSI*DIM
    int*   cnt   = (int*)(xB + (size_t)NSI * DIM);    // 2*NBLK
    int*   lrows = cnt + 2 * NBLK;                    // 2*NBLK*CAP_B
    float* lvecs = (float*)(lrows + 2 * NBLK * CAP_B);// 2*NBLK*CAP_B*16

    const float* xp = x0;
    // scans of x_0 .. x_{steps-2}
    for (int s = 0; s + 1 < steps; ++s) {
        const int upd = (s > 0);
        const int li = (s - 1) & 1, lo = s & 1;
        float a = 0.1f;
        for (int k = 1; k < s; ++k) a *= 0.995f;      // alpha_{s-1}
        const int mix = (upd && ((s - 1) % 25 == 0)) ? 1 : 0;
        float* xc = (s & 1) ? xA : xB;
        scan_kernel<<<NBLK, 256, 0, stream>>>(
            xp, upd ? noise + (size_t)(s - 1) * NSI * DIM : x0,
            upd ? a : 0.0f, mix, upd, xc,
            cnt + li * NBLK, lrows + li * NBLK * CAP_B,
            lvecs + (size_t)li * NBLK * CAP_B * 16, upd,
            cnt + lo * NBLK, lrows + lo * NBLK * CAP_B,
            lvecs + (size_t)lo * NBLK * CAP_B * 16);
        if (upd) xp = xc;
    }
    // fused: build x_{steps-1} (update steps-2), scan it, apply update steps-1
    {
        const int li = (steps - 2) & 1;
        const int updA = (steps >= 2);
        float aA = 0.1f;
        for (int k = 1; k < steps - 1; ++k) aA *= 0.995f;  // alpha_{steps-2}
        const int mixA = (updA && ((steps - 2) % 25 == 0)) ? 1 : 0;
        float aB = 0.1f;
        for (int k = 1; k < steps; ++k) aB *= 0.995f;      // alpha_{steps-1}
        const int mixB = ((steps - 1) % 25 == 0) ? 1 : 0;
        final_kernel<<<SPECIES * (POP / ITR), 256, 0, stream>>>(
            xp, updA ? noise + (size_t)(steps - 2) * NSI * DIM : x0,
            updA ? aA : 0.0f, mixA, updA,
            noise + (size_t)(steps - 1) * NSI * DIM, aB, mixB,
            cnt + li * NBLK, lrows + li * NBLK * CAP_B,
            lvecs + (size_t)li * NBLK * CAP_B * 16, updA,
            (float*)d_out);
    }
}

// Round 7
// 128.175 us; speedup vs baseline: 1.1564x; 1.1564x over previous
//
#include <hip/hip_runtime.h>

// Firefly optimizer, round 7: same 4-dispatch structure as R6 (3 scans +
// fused scan+final; each scan needs the previous scan's complete hot list,
// so 4 dispatches is the structural minimum), but final_kernel rebuilt for
// latency hiding: 256 blocks (64 i-rows each -> all 256 CUs busy) x 512
// threads (8 waves -> 2 waves/SIMD), and all bf16 LDS row writes vectorized
// to ds_write_b128 pairs (R6 showed 424K bank conflicts from u16 writes).
// Gate math unchanged since R3 (passed 4x): D = g_bf16 + (T-sqi)/2, hot <=>
// D > sqj/2; exact-fp32 slow path; hot pairs carried as compact lists.

#define SPECIES 4
#define POP     4096
#define DIM     16
#define NSI     (SPECIES * POP)
#define T_CUT   10.0f
#define NBLK    512        // scan grid: 4 species x 32 itiles x 4 jchunks
#define CAP_B   64         // hot-list entries per block
#define LCAP    128        // compacted list cap (expected ~6)
#define ITR     128        // i-rows per scan block
#define FITR    64         // i-rows per final block
#define JSPAN   1024       // j-rows per LDS tile

typedef __attribute__((ext_vector_type(8)))  short short8;    // 8 bf16
typedef __attribute__((ext_vector_type(16))) float floatx16;  // MFMA C/D

__device__ __forceinline__ unsigned short f2bf(float f) {
    unsigned u = __float_as_uint(f);
    u += 0x7FFFu + ((u >> 16) & 1u);
    return (unsigned short)(u >> 16);
}

// one row of 16 bf16 as two 16B LDS stores (dst 16B-aligned, row = 32B)
__device__ __forceinline__ void store_row_bf16(unsigned short* dst,
                                               const float v[16]) {
    short8 a, b;
    #pragma unroll
    for (int d = 0; d < 8; ++d) {
        a[d] = (short)f2bf(v[d]);
        b[d] = (short)f2bf(v[d + 8]);
    }
    ((short8*)dst)[0] = a;
    ((short8*)dst)[1] = b;
}

// Exact fp32 updated position of `row` at this step (post-mix indexing).
__device__ __forceinline__ void compute_x16(
        const float* __restrict__ xprev, const float* __restrict__ nz,
        float alpha, int mix, int upd, int row,
        const int* __restrict__ lrow, const float* __restrict__ lvec, int nl,
        float v[16]) {
    int src = row;
    if (upd && mix) {
        int i = row & (POP - 1);
        if (i >= POP / 2)
            src = ((((row >> 12) + SPECIES - 1) & (SPECIES - 1)) << 12) | i;
    }
    const float* xp = xprev + (size_t)src * DIM;
    if (!upd) {
        #pragma unroll
        for (int d = 0; d < 16; ++d) v[d] = xp[d];
        return;
    }
    const float* np = nz + (size_t)src * DIM;
    float add[16];
    #pragma unroll
    for (int d = 0; d < 16; ++d) add[d] = 0.0f;
    for (int e = 0; e < nl; ++e) {        // nl ~ 6
        if (lrow[e] == src) {
            #pragma unroll
            for (int d = 0; d < 16; ++d) add[d] += lvec[e * 16 + d];
        }
    }
    #pragma unroll
    for (int d = 0; d < 16; ++d) {
        float xn = (xp[d] + add[d]) + alpha * (np[d] - 0.5f) * 8.0f;
        v[d] = fminf(fmaxf(xn, -4.0f), 4.0f);
    }
}

__device__ __forceinline__ float cost16(const float v[16]) {
    float sqv = 0.0f, cv = 0.0f;
    #pragma unroll
    for (int d = 0; d < 16; ++d) {
        sqv = fmaf(v[d], v[d], sqv);
        cv += cospif(2.0f * v[d]);
    }
    return 10.0f * DIM + sqv - 10.0f * cv;
}

// ---- scan: build x_s tile in LDS, MFMA gate, export hot list ---------------
__global__ __launch_bounds__(256) void scan_kernel(
        const float* __restrict__ xprev, const float* __restrict__ nz,
        float alpha, int mix, int upd,
        float* __restrict__ xcur,                       // materialize x_s
        const int* __restrict__ cin, const int* __restrict__ rin,
        const float* __restrict__ vin, int have_in,
        int* __restrict__ cout, int* __restrict__ rout,
        float* __restrict__ vout) {
    __shared__ unsigned short xb_i[ITR * DIM];          //  4 KB
    __shared__ unsigned short xb_j[JSPAN * DIM];        // 32 KB
    __shared__ float sq_i[ITR];
    __shared__ float sq_j[JSPAN];                       //  4 KB
    __shared__ int   lrow[LCAP];
    __shared__ float lvec[LCAP * 16];                   //  8 KB
    __shared__ int   nl_s, cnt_s;

    const int tid = threadIdx.x;
    const int b   = blockIdx.x;
    const int jc  = b & 3;
    const int it  = (b >> 2) & 31;
    const int sp  = b >> 7;
    const int sb  = sp * POP;
    const int i0  = it * ITR;
    const int j0  = jc * JSPAN;

    if (tid == 0) { nl_s = 0; cnt_s = 0; }
    __syncthreads();

    if (have_in) {
        for (int t = tid; t < NBLK; t += 256) {
            int c = cin[t];
            if (c > 0) {
                c = min(c, CAP_B);
                int base = atomicAdd(&nl_s, c);
                for (int e = 0; e < c; ++e) {
                    int slot = base + e;
                    if (slot < LCAP) {
                        lrow[slot] = rin[t * CAP_B + e];
                        for (int d = 0; d < 16; ++d)
                            lvec[slot * 16 + d] = vin[(t * CAP_B + e) * 16 + d];
                    }
                }
            }
        }
    }
    __syncthreads();
    const int nl = min(nl_s, LCAP);

    // phase A: build rows (no cost)
    for (int r = tid; r < ITR + JSPAN; r += 256) {
        int row = (r < ITR) ? (sb + i0 + r) : (sb + j0 + (r - ITR));
        float v[16];
        compute_x16(xprev, nz, alpha, mix, upd, row, lrow, lvec, nl, v);
        float sqv = 0.0f;
        #pragma unroll
        for (int d = 0; d < 16; ++d) sqv = fmaf(v[d], v[d], sqv);
        if (r < ITR) {
            store_row_bf16(xb_i + r * 16, v);
            sq_i[r] = sqv;
            if (upd && jc == 0) {
                float* xo = xcur + (size_t)row * DIM;
                #pragma unroll
                for (int d = 0; d < 16; ++d) xo[d] = v[d];
            }
        } else {
            int jj = r - ITR;
            store_row_bf16(xb_j + jj * 16, v);
            sq_j[jj] = sqv;
        }
    }
    __syncthreads();

    // phase B: MFMA gate
    const int lane = tid & 63, wave = tid >> 6;
    const int l31 = lane & 31, half = lane >> 5;
    const int iw0 = wave * 32;
    const short8* axi = (const short8*)xb_i;
    const short8* axj = (const short8*)xb_j;
    const short8 afrag = axi[((iw0 + l31) << 1) | half];

    floatx16 c;   // row r -> (r&3) + 8*(r>>2) + 4*half
    {
        const float* sp_ = sq_i + iw0 + 4 * half;
        #pragma unroll
        for (int bq = 0; bq < 4; ++bq)
            #pragma unroll
            for (int t2 = 0; t2 < 4; ++t2)
                c[4 * bq + t2] = 0.5f * (T_CUT - sp_[8 * bq + t2]);
    }

    for (int jt = 0; jt < JSPAN; jt += 32) {
        short8 bfrag = axj[((jt + l31) << 1) | half];
        float  hsqj  = 0.5f * sq_j[jt + l31];
        floatx16 d = __builtin_amdgcn_mfma_f32_32x32x16_bf16(afrag, bfrag, c,
                                                             0, 0, 0);
        float m0 = fmaxf(fmaxf(d[0], d[1]),   fmaxf(d[2], d[3]));
        float m1 = fmaxf(fmaxf(d[4], d[5]),   fmaxf(d[6], d[7]));
        float m2 = fmaxf(fmaxf(d[8], d[9]),   fmaxf(d[10], d[11]));
        float m3 = fmaxf(fmaxf(d[12], d[13]), fmaxf(d[14], d[15]));
        float m  = fmaxf(fmaxf(m0, m1), fmaxf(m2, m3));

        if (__any(m > hsqj)) {
            const int jl = jt + l31;
            #pragma unroll 1
            for (int r = 0; r < 16; ++r) {
                if (d[r] > hsqj) {
                    const int il = iw0 + (r & 3) + 8 * (r >> 2) + 4 * half;
                    const int ig = i0 + il, jg = j0 + jl;
                    if (ig != jg) {                 // diagonal: integer reject
                        float xi[16], xj[16];
                        compute_x16(xprev, nz, alpha, mix, upd,
                                    sb + ig, lrow, lvec, nl, xi);
                        compute_x16(xprev, nz, alpha, mix, upd,
                                    sb + jg, lrow, lvec, nl, xj);
                        float dot = 0.0f;
                        #pragma unroll
                        for (int dd = 0; dd < 16; ++dd)
                            dot = fmaf(xi[dd], xj[dd], dot);
                        float d2 = fmaxf(fmaf(-2.0f, dot,
                                              sq_i[il] + sq_j[jl]), 0.0f);
                        if (d2 < T_CUT && cost16(xi) > cost16(xj)) {
                            float w = 2.0f * expf(-d2);
                            int slot = atomicAdd(&cnt_s, 1);
                            if (slot < CAP_B) {
                                int g = b * CAP_B + slot;
                                rout[g] = sb + ig;
                                #pragma unroll
                                for (int dd = 0; dd < 16; ++dd)
                                    vout[g * 16 + dd] = w * (xj[dd] - xi[dd]);
                            }
                        }
                    }
                }
            }
        }
    }
    __syncthreads();
    if (tid == 0) cout[b] = min(cnt_s, CAP_B);
}

// ---- fused last scan + final update -> d_out -------------------------------
// grid 256 blocks = (species, 64-row i-tile); 512 threads = 8 waves
// (2 waves/SIMD). Each block scans ALL j in 4 LDS chunks; wave w handles
// i-subtile (w&1) x j-quarter (w>>1) of each chunk.
__global__ __launch_bounds__(512) void final_kernel(
        const float* __restrict__ xprev,
        const float* __restrict__ nzA, float alphaA, int mixA, int updA,
        const float* __restrict__ nzB, float alphaB, int mixB,
        const int* __restrict__ cin, const int* __restrict__ rin,
        const float* __restrict__ vin, int have_in,
        float* __restrict__ out) {
    __shared__ unsigned short xb_i[FITR * DIM];         //  2 KB
    __shared__ unsigned short xb_j[JSPAN * DIM];        // 32 KB
    __shared__ float xi_f[FITR * DIM];                  //  4 KB
    __shared__ float attr_s[FITR * DIM];                //  4 KB
    __shared__ float sq_i[FITR];
    __shared__ float sq_j[JSPAN];                       //  4 KB
    __shared__ int   lrow[LCAP];
    __shared__ float lvec[LCAP * 16];                   //  8 KB
    __shared__ int   nl_s;

    const int tid = threadIdx.x;
    const int b   = blockIdx.x;        // 0..255
    const int ib  = b & 63;
    const int sp  = b >> 6;
    const int sb  = sp * POP;
    const int i0  = ib * FITR;

    if (tid == 0) nl_s = 0;
    __syncthreads();
    if (have_in) {
        for (int t = tid; t < NBLK; t += 512) {
            int c = cin[t];
            if (c > 0) {
                c = min(c, CAP_B);
                int base = atomicAdd(&nl_s, c);
                for (int e = 0; e < c; ++e) {
                    int slot = base + e;
                    if (slot < LCAP) {
                        lrow[slot] = rin[t * CAP_B + e];
                        for (int d = 0; d < 16; ++d)
                            lvec[slot * 16 + d] = vin[(t * CAP_B + e) * 16 + d];
                    }
                }
            }
        }
    }
    __syncthreads();
    const int nl = min(nl_s, LCAP);

    // i-rows (keep fp32 copy for the final update) + zero attraction
    if (tid < FITR) {
        int r = tid;
        float v[16];
        compute_x16(xprev, nzA, alphaA, mixA, updA, sb + i0 + r,
                    lrow, lvec, nl, v);
        float sqv = 0.0f;
        #pragma unroll
        for (int d = 0; d < 16; ++d) {
            xi_f[r * 16 + d] = v[d];
            sqv = fmaf(v[d], v[d], sqv);
        }
        store_row_bf16(xb_i + r * 16, v);
        sq_i[r] = sqv;
    }
    for (int t = tid; t < FITR * DIM; t += 512) attr_s[t] = 0.0f;
    __syncthreads();

    const int lane = tid & 63, wave = tid >> 6;     // wave 0..7
    const int l31 = lane & 31, half = lane >> 5;
    const int itile = (wave & 1) * 32;              // i-subtile
    const int jq    = (wave >> 1) * 256;            // j-quarter within chunk
    const short8* axi = (const short8*)xb_i;
    const short8* axj = (const short8*)xb_j;
    const short8 afrag = axi[((itile + l31) << 1) | half];

    floatx16 c;
    {
        const float* sp_ = sq_i + itile + 4 * half;
        #pragma unroll
        for (int bq = 0; bq < 4; ++bq)
            #pragma unroll
            for (int t2 = 0; t2 < 4; ++t2)
                c[4 * bq + t2] = 0.5f * (T_CUT - sp_[8 * bq + t2]);
    }

    for (int chunk = 0; chunk < POP / JSPAN; ++chunk) {
        const int j0 = chunk * JSPAN;
        __syncthreads();                 // previous chunk's MFMA phase done
        for (int r = tid; r < JSPAN; r += 512) {
            float v[16];
            compute_x16(xprev, nzA, alphaA, mixA, updA, sb + j0 + r,
                        lrow, lvec, nl, v);
            float sqv = 0.0f;
            #pragma unroll
            for (int d = 0; d < 16; ++d) sqv = fmaf(v[d], v[d], sqv);
            store_row_bf16(xb_j + r * 16, v);
            sq_j[r] = sqv;
        }
        __syncthreads();

        for (int jt = jq; jt < jq + 256; jt += 32) {
            short8 bfrag = axj[((jt + l31) << 1) | half];
            float  hsqj  = 0.5f * sq_j[jt + l31];
            floatx16 d = __builtin_amdgcn_mfma_f32_32x32x16_bf16(
                    afrag, bfrag, c, 0, 0, 0);
            float m0 = fmaxf(fmaxf(d[0], d[1]),   fmaxf(d[2], d[3]));
            float m1 = fmaxf(fmaxf(d[4], d[5]),   fmaxf(d[6], d[7]));
            float m2 = fmaxf(fmaxf(d[8], d[9]),   fmaxf(d[10], d[11]));
            float m3 = fmaxf(fmaxf(d[12], d[13]), fmaxf(d[14], d[15]));
            float m  = fmaxf(fmaxf(m0, m1), fmaxf(m2, m3));

            if (__any(m > hsqj)) {
                const int jl = jt + l31;
                #pragma unroll 1
                for (int r = 0; r < 16; ++r) {
                    if (d[r] > hsqj) {
                        const int il = itile + (r & 3) + 8 * (r >> 2) + 4 * half;
                        const int ig = i0 + il, jg = j0 + jl;
                        if (ig != jg) {
                            float xi[16], xj[16];
                            #pragma unroll
                            for (int dd = 0; dd < 16; ++dd)
                                xi[dd] = xi_f[il * 16 + dd];
                            compute_x16(xprev, nzA, alphaA, mixA, updA,
                                        sb + jg, lrow, lvec, nl, xj);
                            float dot = 0.0f;
                            #pragma unroll
                            for (int dd = 0; dd < 16; ++dd)
                                dot = fmaf(xi[dd], xj[dd], dot);
                            float d2 = fmaxf(fmaf(-2.0f, dot,
                                    sq_i[il] + sq_j[jl]), 0.0f);
                            if (d2 < T_CUT && cost16(xi) > cost16(xj)) {
                                float w = 2.0f * expf(-d2);
                                #pragma unroll
                                for (int dd = 0; dd < 16; ++dd)
                                    atomicAdd(&attr_s[il * 16 + dd],
                                              w * (xj[dd] - xi[dd]));
                            }
                        }
                    }
                }
            }
        }
    }
    __syncthreads();

    // final update (mixB kept for steps!=4 generality)
    for (int t = tid; t < FITR * DIM; t += 512) {
        int r = t >> 4, d = t & 15;
        int i = i0 + r;
        int grow = sb + i;
        float xn = xi_f[t] + attr_s[t]
                 + alphaB * (nzB[(size_t)grow * DIM + d] - 0.5f) * 8.0f;
        xn = fminf(fmaxf(xn, -4.0f), 4.0f);
        int s_out = (mixB && i >= POP / 2) ? ((sp + 1) & (SPECIES - 1)) : sp;
        out[((size_t)s_out * POP + i) * DIM + d] = xn;
    }
}

extern "C" void kernel_launch(void* const* d_in, const int* in_sizes, int n_in,
                              void* d_out, int out_size, void* d_ws, size_t ws_size,
                              hipStream_t stream) {
    const float* x0    = (const float*)d_in[0];
    const float* noise = (const float*)d_in[1];
    const int steps = in_sizes[1] / in_sizes[0];      // = 4

    float* f     = (float*)d_ws;
    float* xA    = f;                                 // NSI*DIM
    float* xB    = xA + (size_t)NSI * DIM;            // NSI*DIM
    int*   cnt   = (int*)(xB + (size_t)NSI * DIM);    // 2*NBLK
    int*   lrows = cnt + 2 * NBLK;                    // 2*NBLK*CAP_B
    float* lvecs = (float*)(lrows + 2 * NBLK * CAP_B);// 2*NBLK*CAP_B*16

    const float* xp = x0;
    // scans of x_0 .. x_{steps-2}
    for (int s = 0; s + 1 < steps; ++s) {
        const int upd = (s > 0);
        const int li = (s - 1) & 1, lo = s & 1;
        float a = 0.1f;
        for (int k = 1; k < s; ++k) a *= 0.995f;      // alpha_{s-1}
        const int mix = (upd && ((s - 1) % 25 == 0)) ? 1 : 0;
        float* xc = (s & 1) ? xA : xB;
        scan_kernel<<<NBLK, 256, 0, stream>>>(
            xp, upd ? noise + (size_t)(s - 1) * NSI * DIM : x0,
            upd ? a : 0.0f, mix, upd, xc,
            cnt + li * NBLK, lrows + li * NBLK * CAP_B,
            lvecs + (size_t)li * NBLK * CAP_B * 16, upd,
            cnt + lo * NBLK, lrows + lo * NBLK * CAP_B,
            lvecs + (size_t)lo * NBLK * CAP_B * 16);
        if (upd) xp = xc;
    }
    // fused: build x_{steps-1} (update steps-2), scan it, apply update steps-1
    {
        const int li = (steps - 2) & 1;
        const int updA = (steps >= 2);
        float aA = 0.1f;
        for (int k = 1; k < steps - 1; ++k) aA *= 0.995f;  // alpha_{steps-2}
        const int mixA = (updA && ((steps - 2) % 25 == 0)) ? 1 : 0;
        float aB = 0.1f;
        for (int k = 1; k < steps; ++k) aB *= 0.995f;      // alpha_{steps-1}
        const int mixB = ((steps - 1) % 25 == 0) ? 1 : 0;
        final_kernel<<<SPECIES * (POP / FITR), 512, 0, stream>>>(
            xp, updA ? noise + (size_t)(steps - 2) * NSI * DIM : x0,
            updA ? aA : 0.0f, mixA, updA,
            noise + (size_t)(steps - 1) * NSI * DIM, aB, mixB,
            cnt + li * NBLK, lrows + li * NBLK * CAP_B,
            lvecs + (size_t)li * NBLK * CAP_B * 16, updA,
            (float*)d_out);
    }
}